// Round 4
// baseline (115.725 us; speedup 1.0000x reference)
//
#include <hip/hip_runtime.h>

#define K_TOP 300
#define NCLS  80
#define NCAND 2048
#define NBUCK 4096
#define NF4   20000      // float4 per batch (80000 floats)
// thread t owns float4 slots {t + 1024*j, j=0..18}, plus slot 19456+t if t<544

__device__ __forceinline__ unsigned int order_f32(float f) {
    unsigned int u = __float_as_uint(f);
    return u ^ ((u >> 31) ? 0xFFFFFFFFu : 0x80000000u);
}
__device__ __forceinline__ float unorder_f32(unsigned int u) {
    unsigned int v = (u & 0x80000000u) ? (u ^ 0x80000000u) : ~u;
    return __uint_as_float(v);
}

__device__ __forceinline__ uint4 order4(float4 v) {
    uint4 o;
    o.x = order_f32(v.x); o.y = order_f32(v.y);
    o.z = order_f32(v.z); o.w = order_f32(v.w);
    return o;
}

__device__ __forceinline__ void collect1(unsigned int o, int idx, unsigned int B,
                                         unsigned long long* cand,
                                         unsigned int* cur) {
    unsigned int bk = o >> 20;
    if (bk >= B) {
        unsigned int pos = atomicAdd(&cur[bk], 1u);
        if (pos < NCAND)
            cand[pos] = ((unsigned long long)o << 32) |
                        (unsigned long long)(0xFFFFFFFFu - (unsigned int)idx);
    }
}

__device__ __forceinline__ void write_row(float* __restrict__ out, int b, int rank,
                                          unsigned long long key,
                                          const float4* __restrict__ BX,
                                          float sx, float sy) {
    unsigned int o   = (unsigned int)(key >> 32);
    unsigned int idx = ~((unsigned int)key);
    float logit = unorder_f32(o);
    float score = 1.0f / (1.0f + expf(-logit));
    int label = (int)(idx % NCLS);
    int q     = (int)(idx / NCLS);
    float4 bx = BX[q];
    float* po = out + ((size_t)b * K_TOP + rank) * 6;
    po[0] = (float)label;
    po[1] = score;
    po[2] = (bx.x - 0.5f * bx.z) * sx;
    po[3] = (bx.y - 0.5f * bx.w) * sy;
    po[4] = bx.z * sx;
    po[5] = bx.w * sy;
}

__global__ __launch_bounds__(1024) void detr_post_kernel(
    const float* __restrict__ logits,
    const float* __restrict__ boxes,
    const int*   __restrict__ osz,
    float*       __restrict__ out)
{
    __shared__ unsigned int       hist[NBUCK];  // counts -> segment starts
    __shared__ unsigned int       cur[NBUCK];   // fill cursors (end after collect)
    __shared__ unsigned long long cand[NCAND];  // bucket-grouped candidates
    __shared__ unsigned int       csum[1024];
    __shared__ unsigned int       csum2[64];
    __shared__ int s_B;

    const int b = blockIdx.x;
    const int t = threadIdx.x;
    const float4* L4 = (const float4*)(logits + (size_t)b * (NF4 * 4));
    const bool tail = (t < 544);

    for (int i = t; i < NBUCK; i += 1024) hist[i] = 0;
    if (t == 0) s_B = -1;

    // ---- single HBM pass: load entire batch into registers (ordered bits).
    //      20 independent loads in flight per wave; data survives barriers. ----
    uint4 o[20];
    #pragma unroll
    for (int j = 0; j < 19; ++j)
        o[j] = order4(L4[t + j * 1024]);
    if (tail) o[19] = order4(L4[19456 + t]);

    __syncthreads();   // hist init done

    // ---- histogram from registers ----
    #pragma unroll
    for (int j = 0; j < 19; ++j) {
        atomicAdd(&hist[o[j].x >> 20], 1u);
        atomicAdd(&hist[o[j].y >> 20], 1u);
        atomicAdd(&hist[o[j].z >> 20], 1u);
        atomicAdd(&hist[o[j].w >> 20], 1u);
    }
    if (tail) {
        atomicAdd(&hist[o[19].x >> 20], 1u);
        atomicAdd(&hist[o[19].y >> 20], 1u);
        atomicAdd(&hist[o[19].z >> 20], 1u);
        atomicAdd(&hist[o[19].w >> 20], 1u);
    }
    __syncthreads();

    // ---- suffix-scan: hist[bk] -> start[bk] = #keys in buckets > bk,
    //      and B = max bk with start[bk] + cnt[bk] >= K_TOP ----
    csum[t] = hist[4*t] + hist[4*t+1] + hist[4*t+2] + hist[4*t+3];
    __syncthreads();
    if (t < 64) {
        unsigned int s = 0;
        for (int u = 0; u < 16; ++u) s += csum[16*t + u];
        csum2[t] = s;
    }
    __syncthreads();
    if (t == 0) {     // exclusive suffix over the 64 supergroup sums
        unsigned int run = 0;
        for (int s = 63; s >= 0; --s) { unsigned int v = csum2[s]; csum2[s] = run; run += v; }
    }
    __syncthreads();
    {
        unsigned int ex = csum2[t >> 4];
        for (int g2 = (t | 15); g2 > t; --g2) ex += csum[g2];
        unsigned int h0 = hist[4*t], h1 = hist[4*t+1], h2 = hist[4*t+2], h3 = hist[4*t+3];
        unsigned int st3 = ex;
        unsigned int st2 = st3 + h3;
        unsigned int st1 = st2 + h2;
        unsigned int st0 = st1 + h1;
        int bl = -1;   // suffix(>=bk) non-increasing: first hit from top is max
        if      (st3 + h3 >= K_TOP) bl = 4*t + 3;
        else if (st2 + h2 >= K_TOP) bl = 4*t + 2;
        else if (st1 + h1 >= K_TOP) bl = 4*t + 1;
        else if (st0 + h0 >= K_TOP) bl = 4*t + 0;
        if (bl >= 0) atomicMax(&s_B, bl);
        hist[4*t] = st0; hist[4*t+1] = st1; hist[4*t+2] = st2; hist[4*t+3] = st3;
        cur [4*t] = st0; cur [4*t+1] = st1; cur [4*t+2] = st2; cur [4*t+3] = st3;
    }
    __syncthreads();
    const unsigned int B = (unsigned int)s_B;

    // ---- collect candidates from REGISTERS (no memory re-read) ----
    #pragma unroll
    for (int j = 0; j < 19; ++j) {
        const int base = 4 * (t + j * 1024);
        collect1(o[j].x, base + 0, B, cand, cur);
        collect1(o[j].y, base + 1, B, cand, cur);
        collect1(o[j].z, base + 2, B, cand, cur);
        collect1(o[j].w, base + 3, B, cand, cur);
    }
    if (tail) {
        const int base = 4 * (19456 + t);
        collect1(o[19].x, base + 0, B, cand, cur);
        collect1(o[19].y, base + 1, B, cand, cur);
        collect1(o[19].z, base + 2, B, cand, cur);
        collect1(o[19].w, base + 3, B, cand, cur);
    }
    __syncthreads();

    // ---- rank within own bucket segment; write top-300 ----
    const float sx = (float)osz[1];   // scale = [W, H, W, H]
    const float sy = (float)osz[0];
    const float4* BX = (const float4*)(boxes + (size_t)b * 4000);

    int total = (int)cur[B]; if (total > NCAND) total = NCAND;
    for (int i = t; i < total; i += 1024) {
        unsigned long long key = cand[i];
        int bk   = (int)(key >> 52);
        int segS = (int)hist[bk];
        int segE = (int)cur[bk]; if (segE > NCAND) segE = NCAND;
        int r = segS;
        for (int j = segS; j < segE; ++j)
            r += (cand[j] > key) ? 1 : 0;
        if (r < K_TOP)
            write_row(out, b, r, key, BX, sx, sy);
    }
}

extern "C" void kernel_launch(void* const* d_in, const int* in_sizes, int n_in,
                              void* d_out, int out_size, void* d_ws, size_t ws_size,
                              hipStream_t stream) {
    const float* logits = (const float*)d_in[0];
    const float* boxes  = (const float*)d_in[1];
    const int*   osz    = (const int*)d_in[2];
    float* out = (float*)d_out;
    detr_post_kernel<<<dim3(256), dim3(1024), 0, stream>>>(logits, boxes, osz, out);
}

// Round 5
// 40.248 us; speedup vs baseline: 2.8753x; 2.8753x over previous
//
#include <hip/hip_runtime.h>

#define K_TOP 300
#define NCLS  80
#define NCAND 2048
#define NBUCK 4096
#define NF4   20000      // float4 per batch (80000 floats)
#define GTHR  2.2f       // static collect threshold; rank-300 sits at z~2.67

typedef unsigned int       u32;
typedef unsigned long long u64;

__device__ __forceinline__ u32 order_f32(float f) {
    u32 u = __float_as_uint(f);
    return u ^ ((u >> 31) ? 0xFFFFFFFFu : 0x80000000u);
}
__device__ __forceinline__ float unorder_f32(u32 u) {
    u32 v = (u & 0x80000000u) ? (u ^ 0x80000000u) : ~u;
    return __uint_as_float(v);
}

// hot-loop collect: float compare (== ordered compare for positive thresholds)
__device__ __forceinline__ void coll(float v, int idx, u64* cand0, int* pcnt) {
    if (v >= GTHR) {
        u32 o = order_f32(v);
        int pos = atomicAdd(pcnt, 1);
        if (pos < NCAND)
            cand0[pos] = ((u64)o << 32) | (u64)(0xFFFFFFFFu - (u32)idx);
    }
}

// fallback collect (bucket-filtered, cursor-scattered)
__device__ __forceinline__ void collect1(u32 o, int idx, u32 B,
                                         u64* cand, u32* cur) {
    u32 bk = o >> 20;
    if (bk >= B) {
        u32 pos = atomicAdd(&cur[bk], 1u);
        if (pos < NCAND)
            cand[pos] = ((u64)o << 32) | (u64)(0xFFFFFFFFu - (u32)idx);
    }
}

// suffix-scan hist counts -> exclusive-suffix starts (into hist AND cur),
// set *s_B = max bucket with suffix(>=bk) >= K_TOP. Caller barriers before/after.
__device__ __forceinline__ void scan_and_find_B(u32* hist, u32* cur,
                                                u32* csum, u32* csum2,
                                                int* s_B, int t) {
    csum[t] = hist[4*t] + hist[4*t+1] + hist[4*t+2] + hist[4*t+3];
    __syncthreads();
    if (t < 64) {
        u32 s = 0;
        for (int u = 0; u < 16; ++u) s += csum[16*t + u];
        csum2[t] = s;
    }
    __syncthreads();
    if (t == 0) {     // exclusive suffix over the 64 supergroup sums
        u32 run = 0;
        for (int s = 63; s >= 0; --s) { u32 v = csum2[s]; csum2[s] = run; run += v; }
    }
    __syncthreads();
    {
        u32 ex = csum2[t >> 4];
        for (int g2 = (t | 15); g2 > t; --g2) ex += csum[g2];
        u32 h0 = hist[4*t], h1 = hist[4*t+1], h2 = hist[4*t+2], h3 = hist[4*t+3];
        u32 st3 = ex;
        u32 st2 = st3 + h3;
        u32 st1 = st2 + h2;
        u32 st0 = st1 + h1;
        int bl = -1;   // suffix(>=bk) non-increasing: first hit from top is max
        if      (st3 + h3 >= K_TOP) bl = 4*t + 3;
        else if (st2 + h2 >= K_TOP) bl = 4*t + 2;
        else if (st1 + h1 >= K_TOP) bl = 4*t + 1;
        else if (st0 + h0 >= K_TOP) bl = 4*t + 0;
        if (bl >= 0) atomicMax(s_B, bl);
        hist[4*t] = st0; hist[4*t+1] = st1; hist[4*t+2] = st2; hist[4*t+3] = st3;
        cur [4*t] = st0; cur [4*t+1] = st1; cur [4*t+2] = st2; cur [4*t+3] = st3;
    }
}

__device__ __forceinline__ void write_row(float* __restrict__ out, int b, int rank,
                                          u64 key, const float4* __restrict__ BX,
                                          float sx, float sy) {
    u32 o   = (u32)(key >> 32);
    u32 idx = ~((u32)key);
    float logit = unorder_f32(o);
    float score = 1.0f / (1.0f + expf(-logit));
    int label = (int)(idx % NCLS);
    int q     = (int)(idx / NCLS);
    float4 bx = BX[q];
    float* po = out + ((size_t)b * K_TOP + rank) * 6;
    po[0] = (float)label;
    po[1] = score;
    po[2] = (bx.x - 0.5f * bx.z) * sx;
    po[3] = (bx.y - 0.5f * bx.w) * sy;
    po[4] = bx.z * sx;
    po[5] = bx.w * sy;
}

// rank within own bucket segment (cand bucket-grouped); write top-300
__device__ __forceinline__ void rank_and_write(const u64* cand, const u32* hist,
                                               const u32* cur, u32 B, int t, int b,
                                               const float4* BX, float sx, float sy,
                                               float* out) {
    int total = (int)cur[B]; if (total > NCAND) total = NCAND;
    for (int i = t; i < total; i += 1024) {
        u64 key = cand[i];
        int bk   = (int)(key >> 52);
        int segS = (int)hist[bk];
        int segE = (int)cur[bk]; if (segE > NCAND) segE = NCAND;
        int r = segS;
        for (int j = segS; j < segE; ++j)
            r += (cand[j] > key) ? 1 : 0;
        if (r < K_TOP)
            write_row(out, b, r, key, BX, sx, sy);
    }
}

__global__ __launch_bounds__(1024) void detr_post_kernel(
    const float* __restrict__ logits,
    const float* __restrict__ boxes,
    const int*   __restrict__ osz,
    float*       __restrict__ out)
{
    __shared__ u32 hist[NBUCK];    // candidate counts -> segment starts
    __shared__ u32 cur[NBUCK];     // fill cursors (ends after scatter)
    __shared__ u64 cand0[NCAND];   // unordered collected candidates
    __shared__ u64 cand[NCAND];    // bucket-grouped candidates
    __shared__ u32 csum[1024];
    __shared__ u32 csum2[64];
    __shared__ int s_B;
    __shared__ int s_cnt;

    const int b = blockIdx.x;
    const int t = threadIdx.x;
    const float4* L4 = (const float4*)(logits + (size_t)b * (NF4 * 4));
    const bool tail = (t < 544);

    if (t == 0) s_cnt = 0;
    __syncthreads();

    // ---- single streaming pass: threshold-collect; 8 loads in flight ----
    {
        int i = t;
        #pragma unroll
        for (int c = 0; c < 2; ++c, i += 8192) {
            float4 a0 = L4[i];
            float4 a1 = L4[i + 1024];
            float4 a2 = L4[i + 2048];
            float4 a3 = L4[i + 3072];
            float4 a4 = L4[i + 4096];
            float4 a5 = L4[i + 5120];
            float4 a6 = L4[i + 6144];
            float4 a7 = L4[i + 7168];
            #define COLL4(v, slot)                              \
                do { const int base_ = 4 * (slot);              \
                     coll((v).x, base_ + 0, cand0, &s_cnt);     \
                     coll((v).y, base_ + 1, cand0, &s_cnt);     \
                     coll((v).z, base_ + 2, cand0, &s_cnt);     \
                     coll((v).w, base_ + 3, cand0, &s_cnt); } while (0)
            COLL4(a0, i);          COLL4(a1, i + 1024);
            COLL4(a2, i + 2048);   COLL4(a3, i + 3072);
            COLL4(a4, i + 4096);   COLL4(a5, i + 5120);
            COLL4(a6, i + 6144);   COLL4(a7, i + 7168);
        }
        // i == t + 16384; slots 16..18 always valid, slot 19456+t for t<544
        float4 a0 = L4[i];
        float4 a1 = L4[i + 1024];
        float4 a2 = L4[i + 2048];
        float4 a3;
        if (tail) a3 = L4[19456 + t];
        COLL4(a0, i); COLL4(a1, i + 1024); COLL4(a2, i + 2048);
        if (tail) COLL4(a3, 19456 + t);
    }
    __syncthreads();

    const int rawcnt = s_cnt;
    const int cnt = (rawcnt < NCAND) ? rawcnt : NCAND;
    const u32 BUCKET_G = order_f32(GTHR) >> 20;
    bool fast = (rawcnt >= K_TOP) && (rawcnt <= NCAND);

    const float sx = (float)osz[1];   // scale = [W, H, W, H]
    const float sy = (float)osz[0];
    const float4* BX = (const float4*)(boxes + (size_t)b * 4000);

    if (fast) {
        // histogram ONLY the candidates; suffix counts exact for bk > BUCKET_G
        for (int i = t; i < NBUCK; i += 1024) hist[i] = 0;
        if (t == 0) s_B = -1;
        __syncthreads();
        for (int i = t; i < cnt; i += 1024)
            atomicAdd(&hist[(u32)(cand0[i] >> 52)], 1u);
        __syncthreads();
        scan_and_find_B(hist, cur, csum, csum2, &s_B, t);
        __syncthreads();
        fast = (s_B > (int)BUCKET_G);   // B valid only if above collect bucket
    }

    if (fast) {
        const u32 B = (u32)s_B;
        // scatter candidates bucket-grouped via cursors
        for (int i = t; i < cnt; i += 1024) {
            u64 k = cand0[i];
            u32 pos = atomicAdd(&cur[(u32)(k >> 52)], 1u);
            if (pos < NCAND) cand[pos] = k;
        }
        __syncthreads();
        rank_and_write(cand, hist, cur, B, t, b, BX, sx, sy, out);
    } else {
        // ---- fallback (degenerate data only): full two-pass, always correct ----
        for (int i = t; i < NBUCK; i += 1024) hist[i] = 0;
        if (t == 0) s_B = -1;
        __syncthreads();
        for (int i = t; i < NF4; i += 1024) {
            float4 v = L4[i];
            atomicAdd(&hist[order_f32(v.x) >> 20], 1u);
            atomicAdd(&hist[order_f32(v.y) >> 20], 1u);
            atomicAdd(&hist[order_f32(v.z) >> 20], 1u);
            atomicAdd(&hist[order_f32(v.w) >> 20], 1u);
        }
        __syncthreads();
        scan_and_find_B(hist, cur, csum, csum2, &s_B, t);
        __syncthreads();
        const u32 B = (u32)s_B;
        for (int i = t; i < NF4; i += 1024) {
            float4 v = L4[i];
            collect1(order_f32(v.x), 4*i + 0, B, cand, cur);
            collect1(order_f32(v.y), 4*i + 1, B, cand, cur);
            collect1(order_f32(v.z), 4*i + 2, B, cand, cur);
            collect1(order_f32(v.w), 4*i + 3, B, cand, cur);
        }
        __syncthreads();
        rank_and_write(cand, hist, cur, B, t, b, BX, sx, sy, out);
    }
}

extern "C" void kernel_launch(void* const* d_in, const int* in_sizes, int n_in,
                              void* d_out, int out_size, void* d_ws, size_t ws_size,
                              hipStream_t stream) {
    const float* logits = (const float*)d_in[0];
    const float* boxes  = (const float*)d_in[1];
    const int*   osz    = (const int*)d_in[2];
    float* out = (float*)d_out;
    detr_post_kernel<<<dim3(256), dim3(1024), 0, stream>>>(logits, boxes, osz, out);
}